// Round 11
// baseline (27.206 us; speedup 1.0000x reference)
//
#include <hip/hip_runtime.h>

static constexpr int TPB = 256;
static constexpr int NSLICE = 4;   // slices per batch row
static constexpr int ROWB = 8;     // rows per kemit block (gx chunk reused)
static constexpr int PF = 2;       // f4 groups per thread in kemit

using f4 = __attribute__((ext_vector_type(4))) float;

__device__ __forceinline__ float wave_reduce_f32(float v) {
#pragma unroll
    for (int off = 32; off > 0; off >>= 1)
        v += __shfl_down(v, off, 64);
    return v;
}

// ---------------------------------------------------------------------------
// Kernel 1: per-(batch,slice) weighted moment partial sums. Grid (NSLICE,B+1).
// Row b<B, slice s: spart[(b*NSLICE+s)*12 + {0..11}] =
//   Sax, Say, Saxx, Saxy, Sayy, Saa   (weights a, geo_x)
//   Sbx, Sby, Sbxx, Sbxy, Sbyy, Sbb   (weights b, geo_y)
// Sa/Sb not accumulated (rows normalized; solver uses Sa=Sb=1 — validated R9).
// Row b==B: unweighted geo_x moment partials -> gpart[s*5 + {x,y,xx,xy,yy}].
//
// MLP-maxed structure (R10 lesson: batching loads = the win; this kernel is
// latency/MLP-bound): ALL 24 per-thread f4 loads issued in one burst, then
// compute. Load regs are short-lived (~96 VGPR burst + 12 acc ≈ 126 total);
// R7's scratch demotion came from 28 LONG-LIVED accumulators, not load bursts.
// ---------------------------------------------------------------------------
__global__ __launch_bounds__(TPB) void kstats(const float* __restrict__ gx,
                                              const float* __restrict__ gy,
                                              const float* __restrict__ a,
                                              const float* __restrict__ bw,
                                              int N, int B,
                                              double* __restrict__ spart,
                                              double* __restrict__ gpart) {
    const int s = blockIdx.x;
    const int b = blockIdx.y;
    const int n4   = N / 4;          // float4 groups per row
    const int per  = n4 / NSLICE;    // groups per slice (1024)
    const int base = s * per;
    const f4* gx4 = reinterpret_cast<const f4*>(gx);
    const int lane = threadIdx.x & 63, wid = threadIdx.x >> 6;

    if (b == B) {
        // unweighted geo_x moments for this slice
        float sx = 0, sy = 0, sxx = 0, sxy = 0, syy = 0;
        for (int i = base + threadIdx.x; i < base + per; i += TPB) {
            f4 g0 = gx4[2 * i], g1 = gx4[2 * i + 1];
            float x0 = g0[0], y0 = g0[1], x1 = g0[2], y1 = g0[3];
            float x2 = g1[0], y2 = g1[1], x3 = g1[2], y3 = g1[3];
            sx  += (x0 + x1) + (x2 + x3);
            sy  += (y0 + y1) + (y2 + y3);
            sxx += x0 * x0 + x1 * x1 + x2 * x2 + x3 * x3;
            sxy += x0 * y0 + x1 * y1 + x2 * y2 + x3 * y3;
            syy += y0 * y0 + y1 * y1 + y2 * y2 + y3 * y3;
        }
        float accg[5] = {sx, sy, sxx, sxy, syy};
        __shared__ double redg[4][5];
#pragma unroll
        for (int k = 0; k < 5; k++) {
            float v = wave_reduce_f32(accg[k]);
            if (lane == 0) redg[wid][k] = (double)v;
        }
        __syncthreads();
        if (threadIdx.x < 5)
            gpart[s * 5 + threadIdx.x] = redg[0][threadIdx.x] + redg[1][threadIdx.x] +
                                         redg[2][threadIdx.x] + redg[3][threadIdx.x];
        return;
    }

    const f4* a4  = reinterpret_cast<const f4*>(a  + (size_t)b * N);
    const f4* b4  = reinterpret_cast<const f4*>(bw + (size_t)b * N);
    const f4* gy4 = reinterpret_cast<const f4*>(gy);

    float acc[12];
#pragma unroll
    for (int k = 0; k < 12; k++) acc[k] = 0.0f;

    // exactly 4 iterations/thread (per==1024, TPB==256): one 24-load burst.
    const int i0 = base + threadIdx.x;
    f4 av[4], bv[4], gA[4], gB[4], hA[4], hB[4];
#pragma unroll
    for (int q = 0; q < 4; q++) {
        const int i = i0 + q * TPB;
        av[q] = a4[i];
        bv[q] = b4[i];
        gA[q] = gx4[2 * i];
        gB[q] = gx4[2 * i + 1];
        hA[q] = gy4[2 * i];
        hB[q] = gy4[2 * i + 1];
    }

#pragma unroll
    for (int q = 0; q < 4; q++) {
        float wa[4] = {av[q][0], av[q][1], av[q][2], av[q][3]};
        float wb[4] = {bv[q][0], bv[q][1], bv[q][2], bv[q][3]};
        float px[4] = {gA[q][0], gA[q][2], gB[q][0], gB[q][2]};
        float py[4] = {gA[q][1], gA[q][3], gB[q][1], gB[q][3]};
        float qx[4] = {hA[q][0], hA[q][2], hB[q][0], hB[q][2]};
        float qy[4] = {hA[q][1], hA[q][3], hB[q][1], hB[q][3]};
#pragma unroll
        for (int j = 0; j < 4; j++) {
            float w = wa[j], x = px[j], y = py[j];
            float wx = w * x, wy = w * y;
            acc[0] += wx;
            acc[1] += wy;
            acc[2] += wx * x;
            acc[3] += wx * y;
            acc[4] += wy * y;
            acc[5] += w * w;
            float v = wb[j], u = qx[j], t = qy[j];
            float vu = v * u, vt = v * t;
            acc[6]  += vu;
            acc[7]  += vt;
            acc[8]  += vu * u;
            acc[9]  += vu * t;
            acc[10] += vt * t;
            acc[11] += v * v;
        }
    }

    __shared__ double red[4][12];
#pragma unroll
    for (int k = 0; k < 12; k++) {
        float v = wave_reduce_f32(acc[k]);
        if (lane == 0) red[wid][k] = (double)v;
    }
    __syncthreads();
    if (threadIdx.x < 12) {
        spart[((size_t)b * NSLICE + s) * 12 + threadIdx.x] =
            red[0][threadIdx.x] + red[1][threadIdx.x] +
            red[2][threadIdx.x] + red[3][threadIdx.x];
    }
}

// ---------------------------------------------------------------------------
// Kernel 2 (fused solve+emit, ROWB rows per block). Grid ((N/4)/(TPB*PF),
// B/ROWB) = (8, 64) blocks. Each block loads its gx chunk ONCE (PF f4/thread)
// and emits ROWB=8 rows -> gx L2 traffic drops 8x vs row-per-block. Lanes
// 0..ROWB-1 each run one row's closed-form 2x2 SPD OT solve in f64
// (data-parallel, no divergence among them), folding the row-mean constant
//   K = cxx*Ex2 + cyy*Ey2 + cxy*Exy + cx*Ex + cy*Ey
// so the emit inner loop is 5 FMA/point/row:
//   f = x*(cxx*x + cxy*y + cx) + (cyy*y + cy)*y - K
// NT f4 stores (write-once; keep L3 for a/b).
// ---------------------------------------------------------------------------
__global__ __launch_bounds__(TPB) void kemit(const float* __restrict__ gx,
                                             const double* __restrict__ spart,
                                             const double* __restrict__ gpart,
                                             int N, float* __restrict__ out) {
    const int b0 = blockIdx.y * ROWB;
    __shared__ float shc[ROWB][8];   // cxx, cyy, cxy, cx, cy, K

    // issue gx loads first — independent of the solves
    const f4* gx4 = reinterpret_cast<const f4*>(gx);
    const int i0 = blockIdx.x * (TPB * PF) + threadIdx.x;
    f4 g[2 * PF];
#pragma unroll
    for (int k = 0; k < PF; k++) {
        g[2 * k]     = gx4[2 * (i0 + k * TPB)];
        g[2 * k + 1] = gx4[2 * (i0 + k * TPB) + 1];
    }

    if (threadIdx.x < ROWB) {
        const int r = b0 + threadIdx.x;
        double s12[12];
#pragma unroll
        for (int k = 0; k < 12; k++) {
            double t = 0;
#pragma unroll
            for (int s = 0; s < NSLICE; s++)
                t += spart[((size_t)r * NSLICE + s) * 12 + k];
            s12[k] = t;
        }
        double gm[5];
#pragma unroll
        for (int k = 0; k < 5; k++) {
            double t = 0;
#pragma unroll
            for (int s = 0; s < NSLICE; s++) t += gpart[s * 5 + k];
            gm[k] = t / (double)N;
        }

        double mx  = s12[0],  my  = s12[1],  Saxx = s12[2],  Saxy = s12[3],  Sayy = s12[4],  Saa = s12[5];
        double mbx = s12[6],  mby = s12[7],  Sbxx = s12[8],  Sbxy = s12[9],  Sbyy = s12[10], Sbb = s12[11];

        double da = 1.0 - Saa, db = 1.0 - Sbb;
        // cov = (Σ w p p' - m m') / denom  (Sa = Sb = 1: rows are normalized)
        double Caxx = (Saxx - mx * mx) / da;
        double Caxy = (Saxy - mx * my) / da;
        double Cayy = (Sayy - my * my) / da;
        double Cbxx = (Sbxx - mbx * mbx) / db;
        double Cbxy = (Sbxy - mbx * mby) / db;
        double Cbyy = (Sbyy - mby * mby) / db;

        // R = sqrt(cov_a) = (C + sqrt(det C) I) / sqrt(tr C + 2 sqrt(det C))
        double s0 = sqrt(fmax(Caxx * Cayy - Caxy * Caxy, 0.0));
        double t0 = sqrt(Caxx + Cayy + 2.0 * s0);
        double Rxx = (Caxx + s0) / t0, Rxy = Caxy / t0, Ryy = (Cayy + s0) / t0;
        double detR = Rxx * Ryy - Rxy * Rxy;
        double Ixx = Ryy / detR, Ixy = -Rxy / detR, Iyy = Rxx / detR;  // R^{-1}

        // mid = R cov_b R (symmetric)
        double Txx = Cbxx * Rxx + Cbxy * Rxy;
        double Txy = Cbxx * Rxy + Cbxy * Ryy;
        double Tyx = Cbxy * Rxx + Cbyy * Rxy;
        double Tyy = Cbxy * Rxy + Cbyy * Ryy;
        double midxx = Rxx * Txx + Rxy * Tyx;
        double midyy = Rxy * Txy + Ryy * Tyy;
        double midxy = 0.5 * ((Rxx * Txy + Rxy * Tyy) + (Rxy * Txx + Ryy * Tyx));

        // M = sqrt(mid)
        double s1 = sqrt(fmax(midxx * midyy - midxy * midxy, 0.0));
        double t1 = sqrt(midxx + midyy + 2.0 * s1);
        double Mxx = (midxx + s1) / t1, Mxy = midxy / t1, Myy = (midyy + s1) / t1;

        // A = R^{-1} M R^{-1}
        double Uxx = Mxx * Ixx + Mxy * Ixy;
        double Uxy = Mxx * Ixy + Mxy * Iyy;
        double Uyx = Mxy * Ixx + Myy * Ixy;
        double Uyy = Mxy * Ixy + Myy * Iyy;
        double Axx = Ixx * Uxx + Ixy * Uyx;
        double Axy = Ixx * Uxy + Ixy * Uyy;
        double Ayy = Ixy * Uxy + Iyy * Uyy;

        // quadratic-form coefficients + folded row-mean constant K
        double cxx = 1.0 - Axx;
        double cyy = 1.0 - Ayy;
        double cxy = -2.0 * Axy;
        double cx  = 2.0 * (Axx * mx + Axy * my - mbx);
        double cy  = 2.0 * (Ayy * my + Axy * mx - mby);
        double K   = cxx * gm[2] + cyy * gm[4] + cxy * gm[3] + cx * gm[0] + cy * gm[1];
        shc[threadIdx.x][0] = (float)cxx;
        shc[threadIdx.x][1] = (float)cyy;
        shc[threadIdx.x][2] = (float)cxy;
        shc[threadIdx.x][3] = (float)cx;
        shc[threadIdx.x][4] = (float)cy;
        shc[threadIdx.x][5] = (float)K;
    }
    __syncthreads();

#pragma unroll
    for (int r = 0; r < ROWB; r++) {
        const float cxx = shc[r][0], cyy = shc[r][1], cxy = shc[r][2];
        const float cx = shc[r][3], cy = shc[r][4], K = shc[r][5];
        f4* out4 = reinterpret_cast<f4*>(out + (size_t)(b0 + r) * N);
#pragma unroll
        for (int k = 0; k < PF; k++) {
            f4 g0 = g[2 * k], g1 = g[2 * k + 1];
            float rx[4] = {g0[0], g0[2], g1[0], g1[2]};
            float ry[4] = {g0[1], g0[3], g1[1], g1[3]};
            f4 o;
#pragma unroll
            for (int j = 0; j < 4; j++) {
                float x = rx[j], y = ry[j];
                // f = x*(cxx*x + cxy*y + cx) + (cyy*y + cy)*y - K   (5 FMA-class ops)
                float t1v = fmaf(cyy, y, cy);
                float t2v = fmaf(y, t1v, -K);
                float t3v = fmaf(cxx, x, cx);
                float t4v = fmaf(cxy, y, t3v);
                o[j] = fmaf(x, t4v, t2v);
            }
            __builtin_nontemporal_store(o, out4 + (i0 + k * TPB));
        }
    }
}

// ---------------------------------------------------------------------------
extern "C" void kernel_launch(void* const* d_in, const int* in_sizes, int n_in,
                              void* d_out, int out_size, void* d_ws, size_t ws_size,
                              hipStream_t stream) {
    const float* geo_x = (const float*)d_in[0];
    const float* geo_y = (const float*)d_in[1];
    const float* a     = (const float*)d_in[2];
    const float* b     = (const float*)d_in[3];
    float* out = (float*)d_out;

    int N = in_sizes[0] / 2;       // 16384
    int B = in_sizes[2] / N;       // 512

    char* ws = (char*)d_ws;
    double* gpart = (double*)ws;                                   // NSLICE*5 doubles
    double* spart = (double*)(ws + 512);                           // B*NSLICE*12 doubles

    kstats<<<dim3(NSLICE, B + 1), TPB, 0, stream>>>(geo_x, geo_y, a, b, N, B,
                                                    spart, gpart);
    kemit<<<dim3((N / 4) / (TPB * PF), B / ROWB), TPB, 0, stream>>>(geo_x, spart,
                                                                    gpart, N, out);
}

// Round 12
// 26.874 us; speedup vs baseline: 1.0124x; 1.0124x over previous
//
#include <hip/hip_runtime.h>

static constexpr int TPB = 256;
static constexpr int NSLICE = 4;   // slices per batch row
static constexpr int ROWB = 4;     // rows per kemit block (gx chunk reused)
static constexpr int PF = 2;       // f4 groups per thread in kemit

using f4 = __attribute__((ext_vector_type(4))) float;

__device__ __forceinline__ float wave_reduce_f32(float v) {
#pragma unroll
    for (int off = 32; off > 0; off >>= 1)
        v += __shfl_down(v, off, 64);
    return v;
}

// ---------------------------------------------------------------------------
// Kernel 1: per-(batch,slice) weighted moment partial sums. Grid (NSLICE,B+1).
// EXACTLY the R10 version (proven 26.2 µs total): two batches of 12 f4 loads
// keep ~12 loads in flight with VGPR <= 128 (4 waves/SIMD). R11's 24-load
// burst crossed the 128-VGPR occupancy tier and was a wash.
// Row b<B, slice s: spart[(b*NSLICE+s)*12 + {0..11}] =
//   Sax, Say, Saxx, Saxy, Sayy, Saa   (weights a, geo_x)
//   Sbx, Sby, Sbxx, Sbxy, Sbyy, Sbb   (weights b, geo_y)
// Sa/Sb not accumulated (rows normalized; solver uses Sa=Sb=1 — validated R9).
// Row b==B: unweighted geo_x moment partials -> gpart[s*5 + {x,y,xx,xy,yy}].
// ---------------------------------------------------------------------------
__global__ __launch_bounds__(TPB) void kstats(const float* __restrict__ gx,
                                              const float* __restrict__ gy,
                                              const float* __restrict__ a,
                                              const float* __restrict__ bw,
                                              int N, int B,
                                              double* __restrict__ spart,
                                              double* __restrict__ gpart) {
    const int s = blockIdx.x;
    const int b = blockIdx.y;
    const int n4   = N / 4;          // float4 groups per row
    const int per  = n4 / NSLICE;    // groups per slice (1024)
    const int base = s * per;
    const f4* gx4 = reinterpret_cast<const f4*>(gx);
    const int lane = threadIdx.x & 63, wid = threadIdx.x >> 6;

    if (b == B) {
        // unweighted geo_x moments for this slice
        float sx = 0, sy = 0, sxx = 0, sxy = 0, syy = 0;
        for (int i = base + threadIdx.x; i < base + per; i += TPB) {
            f4 g0 = gx4[2 * i], g1 = gx4[2 * i + 1];
            float x0 = g0[0], y0 = g0[1], x1 = g0[2], y1 = g0[3];
            float x2 = g1[0], y2 = g1[1], x3 = g1[2], y3 = g1[3];
            sx  += (x0 + x1) + (x2 + x3);
            sy  += (y0 + y1) + (y2 + y3);
            sxx += x0 * x0 + x1 * x1 + x2 * x2 + x3 * x3;
            sxy += x0 * y0 + x1 * y1 + x2 * y2 + x3 * y3;
            syy += y0 * y0 + y1 * y1 + y2 * y2 + y3 * y3;
        }
        float accg[5] = {sx, sy, sxx, sxy, syy};
        __shared__ double redg[4][5];
#pragma unroll
        for (int k = 0; k < 5; k++) {
            float v = wave_reduce_f32(accg[k]);
            if (lane == 0) redg[wid][k] = (double)v;
        }
        __syncthreads();
        if (threadIdx.x < 5)
            gpart[s * 5 + threadIdx.x] = redg[0][threadIdx.x] + redg[1][threadIdx.x] +
                                         redg[2][threadIdx.x] + redg[3][threadIdx.x];
        return;
    }

    const f4* a4  = reinterpret_cast<const f4*>(a  + (size_t)b * N);
    const f4* b4  = reinterpret_cast<const f4*>(bw + (size_t)b * N);
    const f4* gy4 = reinterpret_cast<const f4*>(gy);

    float acc[12];
#pragma unroll
    for (int k = 0; k < 12; k++) acc[k] = 0.0f;

    // exactly 4 iterations/thread (per==1024, TPB==256): two batches of 2.
    const int i0 = base + threadIdx.x;

#pragma unroll
    for (int half = 0; half < 2; half++) {
        const int ia = i0 + (2 * half) * TPB;
        const int ib = i0 + (2 * half + 1) * TPB;
        // ---- batch: issue 12 independent f4 loads ----
        f4 av0 = a4[ia],  av1 = a4[ib];
        f4 bv0 = b4[ia],  bv1 = b4[ib];
        f4 gA0 = gx4[2 * ia], gA1 = gx4[2 * ia + 1];
        f4 gB0 = gx4[2 * ib], gB1 = gx4[2 * ib + 1];
        f4 hA0 = gy4[2 * ia], hA1 = gy4[2 * ia + 1];
        f4 hB0 = gy4[2 * ib], hB1 = gy4[2 * ib + 1];

        // ---- compute both iterations ----
#pragma unroll
        for (int q = 0; q < 2; q++) {
            f4 av = q ? av1 : av0;
            f4 bv = q ? bv1 : bv0;
            f4 g0 = q ? gB0 : gA0, g1 = q ? gB1 : gA1;
            f4 h0 = q ? hB0 : hA0, h1 = q ? hB1 : hA1;
            float wa[4] = {av[0], av[1], av[2], av[3]};
            float wb[4] = {bv[0], bv[1], bv[2], bv[3]};
            float px[4] = {g0[0], g0[2], g1[0], g1[2]};
            float py[4] = {g0[1], g0[3], g1[1], g1[3]};
            float qx[4] = {h0[0], h0[2], h1[0], h1[2]};
            float qy[4] = {h0[1], h0[3], h1[1], h1[3]};
#pragma unroll
            for (int j = 0; j < 4; j++) {
                float w = wa[j], x = px[j], y = py[j];
                float wx = w * x, wy = w * y;
                acc[0] += wx;
                acc[1] += wy;
                acc[2] += wx * x;
                acc[3] += wx * y;
                acc[4] += wy * y;
                acc[5] += w * w;
                float v = wb[j], u = qx[j], t = qy[j];
                float vu = v * u, vt = v * t;
                acc[6]  += vu;
                acc[7]  += vt;
                acc[8]  += vu * u;
                acc[9]  += vu * t;
                acc[10] += vt * t;
                acc[11] += v * v;
            }
        }
    }

    __shared__ double red[4][12];
#pragma unroll
    for (int k = 0; k < 12; k++) {
        float v = wave_reduce_f32(acc[k]);
        if (lane == 0) red[wid][k] = (double)v;
    }
    __syncthreads();
    if (threadIdx.x < 12) {
        spart[((size_t)b * NSLICE + s) * 12 + threadIdx.x] =
            red[0][threadIdx.x] + red[1][threadIdx.x] +
            red[2][threadIdx.x] + red[3][threadIdx.x];
    }
}

// ---------------------------------------------------------------------------
// Kernel 2 (fused solve+emit, ROWB=4 rows per block). Grid (8, 128) = 1024
// blocks (4 blocks/CU — store parallelism preserved; R11's ROWB=8 at 512
// blocks thinned it). Each block loads its gx chunk ONCE (PF=2 f4-pairs per
// thread, 16 KB/block) and emits 4 rows -> gx L2 traffic 64->16 MB vs
// row-per-block. Lanes 0..3 run the 4 row-solves in f64 data-parallel,
// folding the row-mean constant
//   K = cxx*Ex2 + cyy*Ey2 + cxy*Exy + cx*Ex + cy*Ey
// so the emit inner loop is 5 FMA/point/row:
//   f = x*(cxx*x + cxy*y + cx) + (cyy*y + cy)*y - K
// NT f4 stores (write-once; keep L3 for a/b).
// ---------------------------------------------------------------------------
__global__ __launch_bounds__(TPB) void kemit(const float* __restrict__ gx,
                                             const double* __restrict__ spart,
                                             const double* __restrict__ gpart,
                                             int N, float* __restrict__ out) {
    const int b0 = blockIdx.y * ROWB;
    __shared__ float shc[ROWB][8];   // cxx, cyy, cxy, cx, cy, K

    // issue gx loads first — independent of the solves
    const f4* gx4 = reinterpret_cast<const f4*>(gx);
    const int i0 = blockIdx.x * (TPB * PF) + threadIdx.x;
    f4 g[2 * PF];
#pragma unroll
    for (int k = 0; k < PF; k++) {
        g[2 * k]     = gx4[2 * (i0 + k * TPB)];
        g[2 * k + 1] = gx4[2 * (i0 + k * TPB) + 1];
    }

    if (threadIdx.x < ROWB) {
        const int r = b0 + threadIdx.x;
        double s12[12];
#pragma unroll
        for (int k = 0; k < 12; k++) {
            double t = 0;
#pragma unroll
            for (int s = 0; s < NSLICE; s++)
                t += spart[((size_t)r * NSLICE + s) * 12 + k];
            s12[k] = t;
        }
        double gm[5];
#pragma unroll
        for (int k = 0; k < 5; k++) {
            double t = 0;
#pragma unroll
            for (int s = 0; s < NSLICE; s++) t += gpart[s * 5 + k];
            gm[k] = t / (double)N;
        }

        double mx  = s12[0],  my  = s12[1],  Saxx = s12[2],  Saxy = s12[3],  Sayy = s12[4],  Saa = s12[5];
        double mbx = s12[6],  mby = s12[7],  Sbxx = s12[8],  Sbxy = s12[9],  Sbyy = s12[10], Sbb = s12[11];

        double da = 1.0 - Saa, db = 1.0 - Sbb;
        // cov = (Σ w p p' - m m') / denom  (Sa = Sb = 1: rows are normalized)
        double Caxx = (Saxx - mx * mx) / da;
        double Caxy = (Saxy - mx * my) / da;
        double Cayy = (Sayy - my * my) / da;
        double Cbxx = (Sbxx - mbx * mbx) / db;
        double Cbxy = (Sbxy - mbx * mby) / db;
        double Cbyy = (Sbyy - mby * mby) / db;

        // R = sqrt(cov_a) = (C + sqrt(det C) I) / sqrt(tr C + 2 sqrt(det C))
        double s0 = sqrt(fmax(Caxx * Cayy - Caxy * Caxy, 0.0));
        double t0 = sqrt(Caxx + Cayy + 2.0 * s0);
        double Rxx = (Caxx + s0) / t0, Rxy = Caxy / t0, Ryy = (Cayy + s0) / t0;
        double detR = Rxx * Ryy - Rxy * Rxy;
        double Ixx = Ryy / detR, Ixy = -Rxy / detR, Iyy = Rxx / detR;  // R^{-1}

        // mid = R cov_b R (symmetric)
        double Txx = Cbxx * Rxx + Cbxy * Rxy;
        double Txy = Cbxx * Rxy + Cbxy * Ryy;
        double Tyx = Cbxy * Rxx + Cbyy * Rxy;
        double Tyy = Cbxy * Rxy + Cbyy * Ryy;
        double midxx = Rxx * Txx + Rxy * Tyx;
        double midyy = Rxy * Txy + Ryy * Tyy;
        double midxy = 0.5 * ((Rxx * Txy + Rxy * Tyy) + (Rxy * Txx + Ryy * Tyx));

        // M = sqrt(mid)
        double s1 = sqrt(fmax(midxx * midyy - midxy * midxy, 0.0));
        double t1 = sqrt(midxx + midyy + 2.0 * s1);
        double Mxx = (midxx + s1) / t1, Mxy = midxy / t1, Myy = (midyy + s1) / t1;

        // A = R^{-1} M R^{-1}
        double Uxx = Mxx * Ixx + Mxy * Ixy;
        double Uxy = Mxx * Ixy + Mxy * Iyy;
        double Uyx = Mxy * Ixx + Myy * Ixy;
        double Uyy = Mxy * Ixy + Myy * Iyy;
        double Axx = Ixx * Uxx + Ixy * Uyx;
        double Axy = Ixx * Uxy + Ixy * Uyy;
        double Ayy = Ixy * Uxy + Iyy * Uyy;

        // quadratic-form coefficients + folded row-mean constant K
        double cxx = 1.0 - Axx;
        double cyy = 1.0 - Ayy;
        double cxy = -2.0 * Axy;
        double cx  = 2.0 * (Axx * mx + Axy * my - mbx);
        double cy  = 2.0 * (Ayy * my + Axy * mx - mby);
        double K   = cxx * gm[2] + cyy * gm[4] + cxy * gm[3] + cx * gm[0] + cy * gm[1];
        shc[threadIdx.x][0] = (float)cxx;
        shc[threadIdx.x][1] = (float)cyy;
        shc[threadIdx.x][2] = (float)cxy;
        shc[threadIdx.x][3] = (float)cx;
        shc[threadIdx.x][4] = (float)cy;
        shc[threadIdx.x][5] = (float)K;
    }
    __syncthreads();

#pragma unroll
    for (int r = 0; r < ROWB; r++) {
        const float cxx = shc[r][0], cyy = shc[r][1], cxy = shc[r][2];
        const float cx = shc[r][3], cy = shc[r][4], K = shc[r][5];
        f4* out4 = reinterpret_cast<f4*>(out + (size_t)(b0 + r) * N);
#pragma unroll
        for (int k = 0; k < PF; k++) {
            f4 g0 = g[2 * k], g1 = g[2 * k + 1];
            float rx[4] = {g0[0], g0[2], g1[0], g1[2]};
            float ry[4] = {g0[1], g0[3], g1[1], g1[3]};
            f4 o;
#pragma unroll
            for (int j = 0; j < 4; j++) {
                float x = rx[j], y = ry[j];
                // f = x*(cxx*x + cxy*y + cx) + (cyy*y + cy)*y - K   (5 FMA-class ops)
                float t1v = fmaf(cyy, y, cy);
                float t2v = fmaf(y, t1v, -K);
                float t3v = fmaf(cxx, x, cx);
                float t4v = fmaf(cxy, y, t3v);
                o[j] = fmaf(x, t4v, t2v);
            }
            __builtin_nontemporal_store(o, out4 + (i0 + k * TPB));
        }
    }
}

// ---------------------------------------------------------------------------
extern "C" void kernel_launch(void* const* d_in, const int* in_sizes, int n_in,
                              void* d_out, int out_size, void* d_ws, size_t ws_size,
                              hipStream_t stream) {
    const float* geo_x = (const float*)d_in[0];
    const float* geo_y = (const float*)d_in[1];
    const float* a     = (const float*)d_in[2];
    const float* b     = (const float*)d_in[3];
    float* out = (float*)d_out;

    int N = in_sizes[0] / 2;       // 16384
    int B = in_sizes[2] / N;       // 512

    char* ws = (char*)d_ws;
    double* gpart = (double*)ws;                                   // NSLICE*5 doubles
    double* spart = (double*)(ws + 512);                           // B*NSLICE*12 doubles

    kstats<<<dim3(NSLICE, B + 1), TPB, 0, stream>>>(geo_x, geo_y, a, b, N, B,
                                                    spart, gpart);
    kemit<<<dim3((N / 4) / (TPB * PF), B / ROWB), TPB, 0, stream>>>(geo_x, spart,
                                                                    gpart, N, out);
}

// Round 13
// 26.084 us; speedup vs baseline: 1.0430x; 1.0303x over previous
//
#include <hip/hip_runtime.h>

static constexpr int TPB = 256;
static constexpr int NSLICE = 4;   // slices per batch row

using f4 = __attribute__((ext_vector_type(4))) float;

__device__ __forceinline__ float wave_reduce_f32(float v) {
#pragma unroll
    for (int off = 32; off > 0; off >>= 1)
        v += __shfl_down(v, off, 64);
    return v;
}

// ---------------------------------------------------------------------------
// Kernel 1: per-(batch,slice) weighted moment partial sums. Grid (NSLICE,B+1).
// Row b<B, slice s: spart[(b*NSLICE+s)*12 + {0..11}] =
//   Sax, Say, Saxx, Saxy, Sayy, Saa   (weights a, geo_x)
//   Sbx, Sby, Sbxx, Sbxy, Sbyy, Sbb   (weights b, geo_y)
// Sa/Sb not accumulated (rows normalized; solver uses Sa=Sb=1 — validated R9).
// Row b==B: unweighted geo_x moment partials -> gpart[s*5 + {x,y,xx,xy,yy}].
//
// PROVEN-BEST configuration (26.2 µs total, R10): kstats is latency/MLP-bound;
// two explicit batches of 12 f4 loads keep ~12 loads in flight per wave while
// VGPR stays <= 128 (4 waves/SIMD). Both perturbations are measured WORSE:
//  - 24-load single burst: crosses the 128-VGPR occupancy tier (waves halve,
//    cancels the MLP gain; 27.2 µs).
//  - lighter 6-load batches / two-pass: halves in-flight loads (Little's law;
//    31.1 µs).
// ---------------------------------------------------------------------------
__global__ __launch_bounds__(TPB) void kstats(const float* __restrict__ gx,
                                              const float* __restrict__ gy,
                                              const float* __restrict__ a,
                                              const float* __restrict__ bw,
                                              int N, int B,
                                              double* __restrict__ spart,
                                              double* __restrict__ gpart) {
    const int s = blockIdx.x;
    const int b = blockIdx.y;
    const int n4   = N / 4;          // float4 groups per row
    const int per  = n4 / NSLICE;    // groups per slice (1024)
    const int base = s * per;
    const f4* gx4 = reinterpret_cast<const f4*>(gx);
    const int lane = threadIdx.x & 63, wid = threadIdx.x >> 6;

    if (b == B) {
        // unweighted geo_x moments for this slice
        float sx = 0, sy = 0, sxx = 0, sxy = 0, syy = 0;
        for (int i = base + threadIdx.x; i < base + per; i += TPB) {
            f4 g0 = gx4[2 * i], g1 = gx4[2 * i + 1];
            float x0 = g0[0], y0 = g0[1], x1 = g0[2], y1 = g0[3];
            float x2 = g1[0], y2 = g1[1], x3 = g1[2], y3 = g1[3];
            sx  += (x0 + x1) + (x2 + x3);
            sy  += (y0 + y1) + (y2 + y3);
            sxx += x0 * x0 + x1 * x1 + x2 * x2 + x3 * x3;
            sxy += x0 * y0 + x1 * y1 + x2 * y2 + x3 * y3;
            syy += y0 * y0 + y1 * y1 + y2 * y2 + y3 * y3;
        }
        float accg[5] = {sx, sy, sxx, sxy, syy};
        __shared__ double redg[4][5];
#pragma unroll
        for (int k = 0; k < 5; k++) {
            float v = wave_reduce_f32(accg[k]);
            if (lane == 0) redg[wid][k] = (double)v;
        }
        __syncthreads();
        if (threadIdx.x < 5)
            gpart[s * 5 + threadIdx.x] = redg[0][threadIdx.x] + redg[1][threadIdx.x] +
                                         redg[2][threadIdx.x] + redg[3][threadIdx.x];
        return;
    }

    const f4* a4  = reinterpret_cast<const f4*>(a  + (size_t)b * N);
    const f4* b4  = reinterpret_cast<const f4*>(bw + (size_t)b * N);
    const f4* gy4 = reinterpret_cast<const f4*>(gy);

    float acc[12];
#pragma unroll
    for (int k = 0; k < 12; k++) acc[k] = 0.0f;

    // exactly 4 iterations/thread (per==1024, TPB==256): two batches of 2.
    const int i0 = base + threadIdx.x;

#pragma unroll
    for (int half = 0; half < 2; half++) {
        const int ia = i0 + (2 * half) * TPB;
        const int ib = i0 + (2 * half + 1) * TPB;
        // ---- batch: issue 12 independent f4 loads ----
        f4 av0 = a4[ia],  av1 = a4[ib];
        f4 bv0 = b4[ia],  bv1 = b4[ib];
        f4 gA0 = gx4[2 * ia], gA1 = gx4[2 * ia + 1];
        f4 gB0 = gx4[2 * ib], gB1 = gx4[2 * ib + 1];
        f4 hA0 = gy4[2 * ia], hA1 = gy4[2 * ia + 1];
        f4 hB0 = gy4[2 * ib], hB1 = gy4[2 * ib + 1];

        // ---- compute both iterations ----
#pragma unroll
        for (int q = 0; q < 2; q++) {
            f4 av = q ? av1 : av0;
            f4 bv = q ? bv1 : bv0;
            f4 g0 = q ? gB0 : gA0, g1 = q ? gB1 : gA1;
            f4 h0 = q ? hB0 : hA0, h1 = q ? hB1 : hA1;
            float wa[4] = {av[0], av[1], av[2], av[3]};
            float wb[4] = {bv[0], bv[1], bv[2], bv[3]};
            float px[4] = {g0[0], g0[2], g1[0], g1[2]};
            float py[4] = {g0[1], g0[3], g1[1], g1[3]};
            float qx[4] = {h0[0], h0[2], h1[0], h1[2]};
            float qy[4] = {h0[1], h0[3], h1[1], h1[3]};
#pragma unroll
            for (int j = 0; j < 4; j++) {
                float w = wa[j], x = px[j], y = py[j];
                float wx = w * x, wy = w * y;
                acc[0] += wx;
                acc[1] += wy;
                acc[2] += wx * x;
                acc[3] += wx * y;
                acc[4] += wy * y;
                acc[5] += w * w;
                float v = wb[j], u = qx[j], t = qy[j];
                float vu = v * u, vt = v * t;
                acc[6]  += vu;
                acc[7]  += vt;
                acc[8]  += vu * u;
                acc[9]  += vu * t;
                acc[10] += vt * t;
                acc[11] += v * v;
            }
        }
    }

    __shared__ double red[4][12];
#pragma unroll
    for (int k = 0; k < 12; k++) {
        float v = wave_reduce_f32(acc[k]);
        if (lane == 0) red[wid][k] = (double)v;
    }
    __syncthreads();
    if (threadIdx.x < 12) {
        spart[((size_t)b * NSLICE + s) * 12 + threadIdx.x] =
            red[0][threadIdx.x] + red[1][threadIdx.x] +
            red[2][threadIdx.x] + red[3][threadIdx.x];
    }
}

// ---------------------------------------------------------------------------
// Kernel 2 (fused solve+emit), proven R5/R10 structure. Lanes 0-11 / 64-68
// reduce the row's slice partials into LDS in parallel; thread 0 does the
// closed-form 2x2 SPD OT solve in f64 (Sa=Sb=1) and broadcasts 10 f32
// coefficients via LDS. Geo loads issued BEFORE the barriers so the serial
// solve hides under load latency. Emit:
//   f[b,n] = cxx(x^2-Ex2) + cyy(y^2-Ey2) + cxy(xy-Exy) + cx(x-Ex) + cy(y-Ey)
// with nontemporal float4 stores (write-once; keep L3 for a/b).
// Grid (N/4096, B), 4 float4 per thread. Store-bound at ~6 µs (measured:
// ROWB=4/8 gx-reuse variants are neutral-to-worse — geo is L2-resident).
// ---------------------------------------------------------------------------
__global__ __launch_bounds__(TPB) void kemit(const float* __restrict__ gx,
                                             const double* __restrict__ spart,
                                             const double* __restrict__ gpart,
                                             int N, float* __restrict__ out) {
    const int b = blockIdx.y;
    __shared__ double sh12[12];
    __shared__ double shg[5];
    __shared__ float shc[10];

    // issue geo loads first — independent of the coefficient solve
    const f4* gx4 = reinterpret_cast<const f4*>(gx);
    const int i0 = blockIdx.x * (TPB * 4) + threadIdx.x;
    f4 g[8];
#pragma unroll
    for (int k = 0; k < 4; k++) {
        g[2 * k]     = gx4[2 * (i0 + k * TPB)];
        g[2 * k + 1] = gx4[2 * (i0 + k * TPB) + 1];
    }

    // parallel reduce of slice partials into LDS
    if (threadIdx.x < 12) {
        double t = 0;
#pragma unroll
        for (int s = 0; s < NSLICE; s++)
            t += spart[((size_t)b * NSLICE + s) * 12 + threadIdx.x];
        sh12[threadIdx.x] = t;
    } else if (threadIdx.x >= 64 && threadIdx.x < 69) {
        double t = 0;
#pragma unroll
        for (int s = 0; s < NSLICE; s++) t += gpart[s * 5 + (threadIdx.x - 64)];
        shg[threadIdx.x - 64] = t / (double)N;
    }
    __syncthreads();

    if (threadIdx.x == 0) {
        double mx  = sh12[0],  my  = sh12[1],  Saxx = sh12[2],  Saxy = sh12[3],  Sayy = sh12[4],  Saa = sh12[5];
        double mbx = sh12[6],  mby = sh12[7],  Sbxx = sh12[8],  Sbxy = sh12[9],  Sbyy = sh12[10], Sbb = sh12[11];

        double da = 1.0 - Saa, db = 1.0 - Sbb;
        // cov = (Σ w p p' - m m') / denom  (Sa = Sb = 1: rows are normalized)
        double Caxx = (Saxx - mx * mx) / da;
        double Caxy = (Saxy - mx * my) / da;
        double Cayy = (Sayy - my * my) / da;
        double Cbxx = (Sbxx - mbx * mbx) / db;
        double Cbxy = (Sbxy - mbx * mby) / db;
        double Cbyy = (Sbyy - mby * mby) / db;

        // R = sqrt(cov_a) = (C + sqrt(det C) I) / sqrt(tr C + 2 sqrt(det C))
        double s0 = sqrt(fmax(Caxx * Cayy - Caxy * Caxy, 0.0));
        double t0 = sqrt(Caxx + Cayy + 2.0 * s0);
        double Rxx = (Caxx + s0) / t0, Rxy = Caxy / t0, Ryy = (Cayy + s0) / t0;
        double detR = Rxx * Ryy - Rxy * Rxy;
        double Ixx = Ryy / detR, Ixy = -Rxy / detR, Iyy = Rxx / detR;  // R^{-1}

        // mid = R cov_b R (symmetric)
        double Txx = Cbxx * Rxx + Cbxy * Rxy;
        double Txy = Cbxx * Rxy + Cbxy * Ryy;
        double Tyx = Cbxy * Rxx + Cbyy * Rxy;
        double Tyy = Cbxy * Rxy + Cbyy * Ryy;
        double midxx = Rxx * Txx + Rxy * Tyx;
        double midyy = Rxy * Txy + Ryy * Tyy;
        double midxy = 0.5 * ((Rxx * Txy + Rxy * Tyy) + (Rxy * Txx + Ryy * Tyx));

        // M = sqrt(mid)
        double s1 = sqrt(fmax(midxx * midyy - midxy * midxy, 0.0));
        double t1 = sqrt(midxx + midyy + 2.0 * s1);
        double Mxx = (midxx + s1) / t1, Mxy = midxy / t1, Myy = (midyy + s1) / t1;

        // A = R^{-1} M R^{-1}
        double Uxx = Mxx * Ixx + Mxy * Ixy;
        double Uxy = Mxx * Ixy + Mxy * Iyy;
        double Uyx = Mxy * Ixx + Myy * Ixy;
        double Uyy = Mxy * Ixy + Myy * Iyy;
        double Axx = Ixx * Uxx + Ixy * Uyx;
        double Axy = Ixx * Uxy + Ixy * Uyy;
        double Ayy = Ixy * Uxy + Iyy * Uyy;

        // quadratic-form coefficients; row-mean subtraction cancels the const
        shc[0] = (float)(1.0 - Axx);
        shc[1] = (float)(1.0 - Ayy);
        shc[2] = (float)(-2.0 * Axy);
        shc[3] = (float)(2.0 * (Axx * mx + Axy * my - mbx));
        shc[4] = (float)(2.0 * (Ayy * my + Axy * mx - mby));
        shc[5] = (float)shg[0];
        shc[6] = (float)shg[1];
        shc[7] = (float)shg[2];
        shc[8] = (float)shg[3];
        shc[9] = (float)shg[4];
    }
    __syncthreads();

    const float cxx = shc[0], cyy = shc[1], cxy = shc[2], cx = shc[3], cy = shc[4];
    const float Ex = shc[5], Ey = shc[6], Ex2 = shc[7], Exy = shc[8], Ey2 = shc[9];

    f4* out4 = reinterpret_cast<f4*>(out + (size_t)b * N);
#pragma unroll
    for (int k = 0; k < 4; k++) {
        int i = i0 + k * TPB;
        f4 g0 = g[2 * k], g1 = g[2 * k + 1];
        float rx[4] = {g0[0], g0[2], g1[0], g1[2]};
        float ry[4] = {g0[1], g0[3], g1[1], g1[3]};
        f4 o;
#pragma unroll
        for (int j = 0; j < 4; j++) {
            float x = rx[j], y = ry[j];
            o[j] = cxx * (x * x - Ex2) + cyy * (y * y - Ey2) + cxy * (x * y - Exy) +
                   cx * (x - Ex) + cy * (y - Ey);
        }
        __builtin_nontemporal_store(o, out4 + i);
    }
}

// ---------------------------------------------------------------------------
extern "C" void kernel_launch(void* const* d_in, const int* in_sizes, int n_in,
                              void* d_out, int out_size, void* d_ws, size_t ws_size,
                              hipStream_t stream) {
    const float* geo_x = (const float*)d_in[0];
    const float* geo_y = (const float*)d_in[1];
    const float* a     = (const float*)d_in[2];
    const float* b     = (const float*)d_in[3];
    float* out = (float*)d_out;

    int N = in_sizes[0] / 2;       // 16384
    int B = in_sizes[2] / N;       // 512

    char* ws = (char*)d_ws;
    double* gpart = (double*)ws;                                   // NSLICE*5 doubles
    double* spart = (double*)(ws + 512);                           // B*NSLICE*12 doubles

    kstats<<<dim3(NSLICE, B + 1), TPB, 0, stream>>>(geo_x, geo_y, a, b, N, B,
                                                    spart, gpart);
    kemit<<<dim3((N / 4) / (TPB * 4), B), TPB, 0, stream>>>(geo_x, spart, gpart, N, out);
}

// Round 14
// 26.070 us; speedup vs baseline: 1.0436x; 1.0005x over previous
//
#include <hip/hip_runtime.h>

static constexpr int TPB = 256;
static constexpr int NSLICE = 4;   // slices per batch row

using f4 = __attribute__((ext_vector_type(4))) float;

__device__ __forceinline__ float wave_reduce_f32(float v) {
#pragma unroll
    for (int off = 32; off > 0; off >>= 1)
        v += __shfl_down(v, off, 64);
    return v;
}

// ---------------------------------------------------------------------------
// Kernel 1: per-(batch,slice) weighted moment partial sums. Grid (NSLICE,B+1).
// Row b<B, slice s: spart[(b*NSLICE+s)*12 + {0..11}] =
//   Sax, Say, Saxx, Saxy, Sayy, Saa   (weights a, geo_x)
//   Sbx, Sby, Sbxx, Sbxy, Sbyy, Sbb   (weights b, geo_y)
// Sa/Sb not accumulated (rows normalized; solver uses Sa=Sb=1 — validated R9).
// Row b==B: unweighted geo_x moment partials -> gpart[s*5 + {x,y,xx,xy,yy}].
//
// PROVEN-BEST configuration (26.2 µs total, R10): kstats is latency/MLP-bound;
// two explicit batches of 12 f4 loads keep ~12 loads in flight per wave while
// VGPR stays <= 128 (4 waves/SIMD). Both perturbations are measured WORSE:
//  - 24-load single burst: crosses the 128-VGPR occupancy tier (waves halve,
//    cancels the MLP gain; 27.2 µs).
//  - lighter 6-load batches / two-pass: halves in-flight loads (Little's law;
//    31.1 µs).
// ---------------------------------------------------------------------------
__global__ __launch_bounds__(TPB) void kstats(const float* __restrict__ gx,
                                              const float* __restrict__ gy,
                                              const float* __restrict__ a,
                                              const float* __restrict__ bw,
                                              int N, int B,
                                              double* __restrict__ spart,
                                              double* __restrict__ gpart) {
    const int s = blockIdx.x;
    const int b = blockIdx.y;
    const int n4   = N / 4;          // float4 groups per row
    const int per  = n4 / NSLICE;    // groups per slice (1024)
    const int base = s * per;
    const f4* gx4 = reinterpret_cast<const f4*>(gx);
    const int lane = threadIdx.x & 63, wid = threadIdx.x >> 6;

    if (b == B) {
        // unweighted geo_x moments for this slice
        float sx = 0, sy = 0, sxx = 0, sxy = 0, syy = 0;
        for (int i = base + threadIdx.x; i < base + per; i += TPB) {
            f4 g0 = gx4[2 * i], g1 = gx4[2 * i + 1];
            float x0 = g0[0], y0 = g0[1], x1 = g0[2], y1 = g0[3];
            float x2 = g1[0], y2 = g1[1], x3 = g1[2], y3 = g1[3];
            sx  += (x0 + x1) + (x2 + x3);
            sy  += (y0 + y1) + (y2 + y3);
            sxx += x0 * x0 + x1 * x1 + x2 * x2 + x3 * x3;
            sxy += x0 * y0 + x1 * y1 + x2 * y2 + x3 * y3;
            syy += y0 * y0 + y1 * y1 + y2 * y2 + y3 * y3;
        }
        float accg[5] = {sx, sy, sxx, sxy, syy};
        __shared__ double redg[4][5];
#pragma unroll
        for (int k = 0; k < 5; k++) {
            float v = wave_reduce_f32(accg[k]);
            if (lane == 0) redg[wid][k] = (double)v;
        }
        __syncthreads();
        if (threadIdx.x < 5)
            gpart[s * 5 + threadIdx.x] = redg[0][threadIdx.x] + redg[1][threadIdx.x] +
                                         redg[2][threadIdx.x] + redg[3][threadIdx.x];
        return;
    }

    const f4* a4  = reinterpret_cast<const f4*>(a  + (size_t)b * N);
    const f4* b4  = reinterpret_cast<const f4*>(bw + (size_t)b * N);
    const f4* gy4 = reinterpret_cast<const f4*>(gy);

    float acc[12];
#pragma unroll
    for (int k = 0; k < 12; k++) acc[k] = 0.0f;

    // exactly 4 iterations/thread (per==1024, TPB==256): two batches of 2.
    const int i0 = base + threadIdx.x;

#pragma unroll
    for (int half = 0; half < 2; half++) {
        const int ia = i0 + (2 * half) * TPB;
        const int ib = i0 + (2 * half + 1) * TPB;
        // ---- batch: issue 12 independent f4 loads ----
        f4 av0 = a4[ia],  av1 = a4[ib];
        f4 bv0 = b4[ia],  bv1 = b4[ib];
        f4 gA0 = gx4[2 * ia], gA1 = gx4[2 * ia + 1];
        f4 gB0 = gx4[2 * ib], gB1 = gx4[2 * ib + 1];
        f4 hA0 = gy4[2 * ia], hA1 = gy4[2 * ia + 1];
        f4 hB0 = gy4[2 * ib], hB1 = gy4[2 * ib + 1];

        // ---- compute both iterations ----
#pragma unroll
        for (int q = 0; q < 2; q++) {
            f4 av = q ? av1 : av0;
            f4 bv = q ? bv1 : bv0;
            f4 g0 = q ? gB0 : gA0, g1 = q ? gB1 : gA1;
            f4 h0 = q ? hB0 : hA0, h1 = q ? hB1 : hA1;
            float wa[4] = {av[0], av[1], av[2], av[3]};
            float wb[4] = {bv[0], bv[1], bv[2], bv[3]};
            float px[4] = {g0[0], g0[2], g1[0], g1[2]};
            float py[4] = {g0[1], g0[3], g1[1], g1[3]};
            float qx[4] = {h0[0], h0[2], h1[0], h1[2]};
            float qy[4] = {h0[1], h0[3], h1[1], h1[3]};
#pragma unroll
            for (int j = 0; j < 4; j++) {
                float w = wa[j], x = px[j], y = py[j];
                float wx = w * x, wy = w * y;
                acc[0] += wx;
                acc[1] += wy;
                acc[2] += wx * x;
                acc[3] += wx * y;
                acc[4] += wy * y;
                acc[5] += w * w;
                float v = wb[j], u = qx[j], t = qy[j];
                float vu = v * u, vt = v * t;
                acc[6]  += vu;
                acc[7]  += vt;
                acc[8]  += vu * u;
                acc[9]  += vu * t;
                acc[10] += vt * t;
                acc[11] += v * v;
            }
        }
    }

    __shared__ double red[4][12];
#pragma unroll
    for (int k = 0; k < 12; k++) {
        float v = wave_reduce_f32(acc[k]);
        if (lane == 0) red[wid][k] = (double)v;
    }
    __syncthreads();
    if (threadIdx.x < 12) {
        spart[((size_t)b * NSLICE + s) * 12 + threadIdx.x] =
            red[0][threadIdx.x] + red[1][threadIdx.x] +
            red[2][threadIdx.x] + red[3][threadIdx.x];
    }
}

// ---------------------------------------------------------------------------
// Kernel 2 (fused solve+emit), proven R5/R10 structure. Lanes 0-11 / 64-68
// reduce the row's slice partials into LDS in parallel; thread 0 does the
// closed-form 2x2 SPD OT solve in f64 (Sa=Sb=1) and broadcasts 10 f32
// coefficients via LDS. Geo loads issued BEFORE the barriers so the serial
// solve hides under load latency. Emit:
//   f[b,n] = cxx(x^2-Ex2) + cyy(y^2-Ey2) + cxy(xy-Exy) + cx(x-Ex) + cy(y-Ey)
// with nontemporal float4 stores (write-once; keep L3 for a/b).
// Grid (N/4096, B), 4 float4 per thread. Store-bound at ~6 µs (measured:
// ROWB=4/8 gx-reuse variants are neutral-to-worse — geo is L2-resident).
// ---------------------------------------------------------------------------
__global__ __launch_bounds__(TPB) void kemit(const float* __restrict__ gx,
                                             const double* __restrict__ spart,
                                             const double* __restrict__ gpart,
                                             int N, float* __restrict__ out) {
    const int b = blockIdx.y;
    __shared__ double sh12[12];
    __shared__ double shg[5];
    __shared__ float shc[10];

    // issue geo loads first — independent of the coefficient solve
    const f4* gx4 = reinterpret_cast<const f4*>(gx);
    const int i0 = blockIdx.x * (TPB * 4) + threadIdx.x;
    f4 g[8];
#pragma unroll
    for (int k = 0; k < 4; k++) {
        g[2 * k]     = gx4[2 * (i0 + k * TPB)];
        g[2 * k + 1] = gx4[2 * (i0 + k * TPB) + 1];
    }

    // parallel reduce of slice partials into LDS
    if (threadIdx.x < 12) {
        double t = 0;
#pragma unroll
        for (int s = 0; s < NSLICE; s++)
            t += spart[((size_t)b * NSLICE + s) * 12 + threadIdx.x];
        sh12[threadIdx.x] = t;
    } else if (threadIdx.x >= 64 && threadIdx.x < 69) {
        double t = 0;
#pragma unroll
        for (int s = 0; s < NSLICE; s++) t += gpart[s * 5 + (threadIdx.x - 64)];
        shg[threadIdx.x - 64] = t / (double)N;
    }
    __syncthreads();

    if (threadIdx.x == 0) {
        double mx  = sh12[0],  my  = sh12[1],  Saxx = sh12[2],  Saxy = sh12[3],  Sayy = sh12[4],  Saa = sh12[5];
        double mbx = sh12[6],  mby = sh12[7],  Sbxx = sh12[8],  Sbxy = sh12[9],  Sbyy = sh12[10], Sbb = sh12[11];

        double da = 1.0 - Saa, db = 1.0 - Sbb;
        // cov = (Σ w p p' - m m') / denom  (Sa = Sb = 1: rows are normalized)
        double Caxx = (Saxx - mx * mx) / da;
        double Caxy = (Saxy - mx * my) / da;
        double Cayy = (Sayy - my * my) / da;
        double Cbxx = (Sbxx - mbx * mbx) / db;
        double Cbxy = (Sbxy - mbx * mby) / db;
        double Cbyy = (Sbyy - mby * mby) / db;

        // R = sqrt(cov_a) = (C + sqrt(det C) I) / sqrt(tr C + 2 sqrt(det C))
        double s0 = sqrt(fmax(Caxx * Cayy - Caxy * Caxy, 0.0));
        double t0 = sqrt(Caxx + Cayy + 2.0 * s0);
        double Rxx = (Caxx + s0) / t0, Rxy = Caxy / t0, Ryy = (Cayy + s0) / t0;
        double detR = Rxx * Ryy - Rxy * Rxy;
        double Ixx = Ryy / detR, Ixy = -Rxy / detR, Iyy = Rxx / detR;  // R^{-1}

        // mid = R cov_b R (symmetric)
        double Txx = Cbxx * Rxx + Cbxy * Rxy;
        double Txy = Cbxx * Rxy + Cbxy * Ryy;
        double Tyx = Cbxy * Rxx + Cbyy * Rxy;
        double Tyy = Cbxy * Rxy + Cbyy * Ryy;
        double midxx = Rxx * Txx + Rxy * Tyx;
        double midyy = Rxy * Txy + Ryy * Tyy;
        double midxy = 0.5 * ((Rxx * Txy + Rxy * Tyy) + (Rxy * Txx + Ryy * Tyx));

        // M = sqrt(mid)
        double s1 = sqrt(fmax(midxx * midyy - midxy * midxy, 0.0));
        double t1 = sqrt(midxx + midyy + 2.0 * s1);
        double Mxx = (midxx + s1) / t1, Mxy = midxy / t1, Myy = (midyy + s1) / t1;

        // A = R^{-1} M R^{-1}
        double Uxx = Mxx * Ixx + Mxy * Ixy;
        double Uxy = Mxx * Ixy + Mxy * Iyy;
        double Uyx = Mxy * Ixx + Myy * Ixy;
        double Uyy = Mxy * Ixy + Myy * Iyy;
        double Axx = Ixx * Uxx + Ixy * Uyx;
        double Axy = Ixx * Uxy + Ixy * Uyy;
        double Ayy = Ixy * Uxy + Iyy * Uyy;

        // quadratic-form coefficients; row-mean subtraction cancels the const
        shc[0] = (float)(1.0 - Axx);
        shc[1] = (float)(1.0 - Ayy);
        shc[2] = (float)(-2.0 * Axy);
        shc[3] = (float)(2.0 * (Axx * mx + Axy * my - mbx));
        shc[4] = (float)(2.0 * (Ayy * my + Axy * mx - mby));
        shc[5] = (float)shg[0];
        shc[6] = (float)shg[1];
        shc[7] = (float)shg[2];
        shc[8] = (float)shg[3];
        shc[9] = (float)shg[4];
    }
    __syncthreads();

    const float cxx = shc[0], cyy = shc[1], cxy = shc[2], cx = shc[3], cy = shc[4];
    const float Ex = shc[5], Ey = shc[6], Ex2 = shc[7], Exy = shc[8], Ey2 = shc[9];

    f4* out4 = reinterpret_cast<f4*>(out + (size_t)b * N);
#pragma unroll
    for (int k = 0; k < 4; k++) {
        int i = i0 + k * TPB;
        f4 g0 = g[2 * k], g1 = g[2 * k + 1];
        float rx[4] = {g0[0], g0[2], g1[0], g1[2]};
        float ry[4] = {g0[1], g0[3], g1[1], g1[3]};
        f4 o;
#pragma unroll
        for (int j = 0; j < 4; j++) {
            float x = rx[j], y = ry[j];
            o[j] = cxx * (x * x - Ex2) + cyy * (y * y - Ey2) + cxy * (x * y - Exy) +
                   cx * (x - Ex) + cy * (y - Ey);
        }
        __builtin_nontemporal_store(o, out4 + i);
    }
}

// ---------------------------------------------------------------------------
extern "C" void kernel_launch(void* const* d_in, const int* in_sizes, int n_in,
                              void* d_out, int out_size, void* d_ws, size_t ws_size,
                              hipStream_t stream) {
    const float* geo_x = (const float*)d_in[0];
    const float* geo_y = (const float*)d_in[1];
    const float* a     = (const float*)d_in[2];
    const float* b     = (const float*)d_in[3];
    float* out = (float*)d_out;

    int N = in_sizes[0] / 2;       // 16384
    int B = in_sizes[2] / N;       // 512

    char* ws = (char*)d_ws;
    double* gpart = (double*)ws;                                   // NSLICE*5 doubles
    double* spart = (double*)(ws + 512);                           // B*NSLICE*12 doubles

    kstats<<<dim3(NSLICE, B + 1), TPB, 0, stream>>>(geo_x, geo_y, a, b, N, B,
                                                    spart, gpart);
    kemit<<<dim3((N / 4) / (TPB * 4), B), TPB, 0, stream>>>(geo_x, spart, gpart, N, out);
}